// Round 5
// baseline (164.907 us; speedup 1.0000x reference)
//
#include <hip/hip_runtime.h>
#include <stdint.h>

#define N_CODES 65536
#define CB_DIM 8
#define B_ROWS 16
#define X_COLS 2048
#define M_ROWS 4096            // 16*2048/8
#define RPB 8                  // rows per argmin block
#define THREADS 256

// workspace byte offsets (unchanged footprint: 2,507,008 B — no ws growth)
#define WS_SCALE 0             // 16 f32
#define WS_IDX   256           // 4096 i32
#define WS_U     16640         // 32768 f32  — NOW HOLDS nu = -2*(x/scale)
#define WS_SUMS  147712        // 65536*8 f32
#define WS_CNT   2244864       // 65536 f32

// distance + min-track for one code against 8 rows. nu[] values are loaded
// from global via a UNIFORM address -> s_load -> SGPRs. Each fma reads exactly
// one SGPR source (legal). Products nu*c = (-2u)*c: bit-identical to the
// passing round-0/4 kernels (exact *-2 scaling commutes with rounding).
#define CODE_BODY(C0, C1, NIDX)                                            \
    {                                                                      \
        float hn = (C0).x * (C0).x;                                        \
        hn = fmaf((C0).y, (C0).y, hn);                                     \
        hn = fmaf((C0).z, (C0).z, hn);                                     \
        hn = fmaf((C0).w, (C0).w, hn);                                     \
        hn = fmaf((C1).x, (C1).x, hn);                                     \
        hn = fmaf((C1).y, (C1).y, hn);                                     \
        hn = fmaf((C1).z, (C1).z, hn);                                     \
        hn = fmaf((C1).w, (C1).w, hn);                                     \
        _Pragma("unroll")                                                  \
        for (int r = 0; r < RPB; r++) {                                    \
            float d = hn;                                                  \
            d = fmaf(nu[r * 8 + 0], (C0).x, d);                            \
            d = fmaf(nu[r * 8 + 1], (C0).y, d);                            \
            d = fmaf(nu[r * 8 + 2], (C0).z, d);                            \
            d = fmaf(nu[r * 8 + 3], (C0).w, d);                            \
            d = fmaf(nu[r * 8 + 4], (C1).x, d);                            \
            d = fmaf(nu[r * 8 + 5], (C1).y, d);                            \
            d = fmaf(nu[r * 8 + 6], (C1).z, d);                            \
            d = fmaf(nu[r * 8 + 7], (C1).w, d);                            \
            if (d < best[r]) { best[r] = d; bidx[r] = (NIDX); }            \
        }                                                                  \
    }

// ---------------- prep: per-row scale + nu = -2*(x/scale) ----------------
// Reduction order is VERBATIM the passing kernel's -> bit-identical scale.
__global__ __launch_bounds__(256) void prep_kernel(const float* __restrict__ x,
                                                   float* __restrict__ scale_out,
                                                   float* __restrict__ nuout) {
    int tid = threadIdx.x;
    int xr = blockIdx.x;                               // 0..15
    const float4* xv = (const float4*)(x + xr * X_COLS);
    float4 q0 = xv[tid];
    float4 q1 = xv[tid + 256];
    float s = fabsf(q0.x) + fabsf(q0.y) + fabsf(q0.z) + fabsf(q0.w)
            + fabsf(q1.x) + fabsf(q1.y) + fabsf(q1.z) + fabsf(q1.w);
    #pragma unroll
    for (int off = 32; off > 0; off >>= 1) s += __shfl_down(s, off, 64);
    __shared__ float ls[4];
    __shared__ float scale_sh;
    int wave = tid >> 6, lane = tid & 63;
    if (lane == 0) ls[wave] = s;
    __syncthreads();
    if (tid == 0) {
        float t = (ls[0] + ls[1] + ls[2] + ls[3]) * (1.0f / (float)X_COLS);
        scale_sh = t;
        scale_out[xr] = t;
    }
    __syncthreads();
    float scale = scale_sh;

    // nu = -2*(x/scale): same op composition (div then *-2.0f) as the
    // passing kernels -> bit-identical values.
    float4 n0, n1;
    n0.x = -2.0f * (q0.x / scale);  n0.y = -2.0f * (q0.y / scale);
    n0.z = -2.0f * (q0.z / scale);  n0.w = -2.0f * (q0.w / scale);
    n1.x = -2.0f * (q1.x / scale);  n1.y = -2.0f * (q1.y / scale);
    n1.z = -2.0f * (q1.z / scale);  n1.w = -2.0f * (q1.w / scale);
    float4* np = (float4*)(nuout + xr * X_COLS);
    np[tid]       = n0;
    np[tid + 256] = n1;
}

// ---------------- argmin over the full codebook (pure hot loop) ----------------
__global__ __launch_bounds__(256, 2) void argmin_kernel(const float* __restrict__ cb,
                                                        const float* __restrict__ nuarr,
                                                        int* __restrict__ indices,
                                                        float* __restrict__ sums,
                                                        float* __restrict__ counts) {
    int tid = threadIdx.x;
    int m0 = blockIdx.x * RPB;

    // 64 wave-uniform nu values via UNIFORM-address read-only loads ->
    // s_load_dwordx16 -> SGPR residency. This is the standard scalar path the
    // compiler understands (unlike the asm pins of rounds 0/3: AGPR demotion
    // / miscompile). If it ever spills, it spills correctly.
    const float* __restrict__ up = nuarr + (size_t)m0 * CB_DIM;
    float nu[RPB * CB_DIM];
    #pragma unroll
    for (int i = 0; i < RPB * CB_DIM; i++) nu[i] = up[i];

    float best[RPB];
    int   bidx[RPB];
    #pragma unroll
    for (int r = 0; r < RPB; r++) { best[r] = 3.4e38f; bidx[r] = 0; }

    // ---- 4-wide ping-pong, no rotation copies. Coverage: tid + 256k,
    // k=0..255. Max prefetch index: j=62 -> tid+63488+1792 <= 65535.
    const float4* cp = (const float4*)cb;
    int n = tid;
    float4 a0 = cp[2 * n],           a1 = cp[2 * n + 1];
    float4 b0 = cp[2 * (n + 256)],   b1 = cp[2 * (n + 256) + 1];
    float4 c0 = cp[2 * (n + 512)],   c1 = cp[2 * (n + 512) + 1];
    float4 d0 = cp[2 * (n + 768)],   d1 = cp[2 * (n + 768) + 1];

    for (int j = 0; j < 63; j++) {
        CODE_BODY(a0, a1, n)
        CODE_BODY(b0, b1, n + 256)
        a0 = cp[2 * (n + 1024)]; a1 = cp[2 * (n + 1024) + 1];
        b0 = cp[2 * (n + 1280)]; b1 = cp[2 * (n + 1280) + 1];
        CODE_BODY(c0, c1, n + 512)
        CODE_BODY(d0, d1, n + 768)
        c0 = cp[2 * (n + 1536)]; c1 = cp[2 * (n + 1536) + 1];
        d0 = cp[2 * (n + 1792)]; d1 = cp[2 * (n + 1792) + 1];
        n += 1024;
    }
    CODE_BODY(a0, a1, n)
    CODE_BODY(b0, b1, n + 256)
    CODE_BODY(c0, c1, n + 512)
    CODE_BODY(d0, d1, n + 768)

    // ---- cross-thread reduce: (sortable(dist)<<32)|idx, u64-min ----
    __shared__ unsigned long long red[RPB][THREADS];   // 16 KB
    #pragma unroll
    for (int r = 0; r < RPB; r++) {
        unsigned int b = __float_as_uint(best[r]);
        unsigned int k = b ^ ((unsigned int)((int)b >> 31) | 0x80000000u);
        red[r][tid] = ((unsigned long long)k << 32) | (unsigned int)bidx[r];
    }
    for (int t = THREADS / 2; t > 0; t >>= 1) {
        __syncthreads();
        if (tid < t) {
            #pragma unroll
            for (int r = 0; r < RPB; r++) {
                unsigned long long a = red[r][tid], c = red[r][tid + t];
                if (c < a) red[r][tid] = c;
            }
        }
    }
    __syncthreads();

    // indices + zero sums/counts at selected codes (kernel boundary orders
    // the zeros before accum; duplicate zero-writes are benign)
    if (tid < RPB) {
        int idx = (int)(red[tid][0] & 0xFFFFFFFFull);
        indices[m0 + tid] = idx;
        counts[idx] = 0.f;
        float4 z = make_float4(0.f, 0.f, 0.f, 0.f);
        float4* sp = (float4*)(sums + (size_t)idx * CB_DIM);
        sp[0] = z;
        sp[1] = z;
    }
}

// ---------------- segment-sum via atomics (128 blocks, 1 thr/(m,k)) ----------------
// nuarr holds -2u; sums therefore accumulate -2*sum(u) EXACTLY (power-of-two
// scaling commutes with fp rounding, any atomic order). gather compensates.
__global__ __launch_bounds__(256) void accum_kernel(const int* __restrict__ indices,
                                                    const float* __restrict__ nuarr,
                                                    float* __restrict__ sums,
                                                    float* __restrict__ counts) {
    int e = blockIdx.x * blockDim.x + threadIdx.x;     // 0..32767, one per (m,k)
    int m = e >> 3, k = e & 7;
    int idx = indices[m];
    if (k == 0) atomicAdd(&counts[idx], 1.0f);
    atomicAdd(&sums[(size_t)idx * CB_DIM + k], nuarr[e]);
}

// ---------------- gather + rescale ----------------
__global__ __launch_bounds__(256) void gather_kernel(const int* __restrict__ indices,
                                                     const float* __restrict__ sums,
                                                     const float* __restrict__ counts,
                                                     const float* __restrict__ scale,
                                                     float* __restrict__ out) {
    int e = blockIdx.x * blockDim.x + threadIdx.x;     // 0..32767
    if (e < B_ROWS * X_COLS) {
        int m = e >> 3, k = e & 7;
        int idx = indices[m];
        float c = counts[idx];
        c = c < 1.f ? 1.f : c;
        // sums = -2*S exactly; (-0.5f)*(sums/c) == S/c bit-exactly.
        out[e] = scale[e >> 11] * (-0.5f * (sums[(size_t)idx * CB_DIM + k] / c));
    }
}

extern "C" void kernel_launch(void* const* d_in, const int* in_sizes, int n_in,
                              void* d_out, int out_size, void* d_ws, size_t ws_size,
                              hipStream_t stream) {
    const float* x  = (const float*)d_in[0];           // [16,2048]
    const float* cb = (const float*)d_in[1];           // [65536,8]
    char* ws = (char*)d_ws;
    float* scale   = (float*)(ws + WS_SCALE);
    int*   indices = (int*)(ws + WS_IDX);
    float* nuarr   = (float*)(ws + WS_U);
    float* sums    = (float*)(ws + WS_SUMS);
    float* counts  = (float*)(ws + WS_CNT);
    float* out     = (float*)d_out;

    prep_kernel  <<<B_ROWS, 256, 0, stream>>>(x, scale, nuarr);
    argmin_kernel<<<M_ROWS / RPB, 256, 0, stream>>>(cb, nuarr, indices, sums, counts);
    accum_kernel <<<(M_ROWS * CB_DIM) / 256, 256, 0, stream>>>(indices, nuarr, sums, counts);
    gather_kernel<<<(B_ROWS * X_COLS) / 256, 256, 0, stream>>>(indices, sums, counts, scale, out);
}

// Round 6
// 144.348 us; speedup vs baseline: 1.1424x; 1.1424x over previous
//
#include <hip/hip_runtime.h>
#include <stdint.h>

#define N_CODES 65536
#define CB_DIM 8
#define B_ROWS 16
#define X_COLS 2048
#define M_ROWS 4096            // 16*2048/8
#define RPB 8                  // rows per argmin block
#define AT 512                 // argmin threads/block (8 waves -> 4 waves/SIMD at 2 blk/CU)

// workspace byte offsets (unchanged footprint: 2,507,008 B — no ws growth)
#define WS_SCALE 0             // 16 f32
#define WS_IDX   256           // 4096 i32
#define WS_U     16640         // 32768 f32  — holds nu = -2*(x/scale)
#define WS_SUMS  147712        // 65536*8 f32
#define WS_CNT   2244864       // 65536 f32

// distance + min-track for one code against 8 rows. nu[] values are loaded
// from global via a UNIFORM address -> s_load -> SGPRs (verified round 5:
// SGPR_Count 96, VGPR_Count 40, absmax 0.0). Each fma reads exactly one SGPR
// source (legal). fma chain order unchanged since round 0 -> bit-identical.
#define CODE_BODY(C0, C1, NIDX)                                            \
    {                                                                      \
        float hn = (C0).x * (C0).x;                                        \
        hn = fmaf((C0).y, (C0).y, hn);                                     \
        hn = fmaf((C0).z, (C0).z, hn);                                     \
        hn = fmaf((C0).w, (C0).w, hn);                                     \
        hn = fmaf((C1).x, (C1).x, hn);                                     \
        hn = fmaf((C1).y, (C1).y, hn);                                     \
        hn = fmaf((C1).z, (C1).z, hn);                                     \
        hn = fmaf((C1).w, (C1).w, hn);                                     \
        _Pragma("unroll")                                                  \
        for (int r = 0; r < RPB; r++) {                                    \
            float d = hn;                                                  \
            d = fmaf(nu[r * 8 + 0], (C0).x, d);                            \
            d = fmaf(nu[r * 8 + 1], (C0).y, d);                            \
            d = fmaf(nu[r * 8 + 2], (C0).z, d);                            \
            d = fmaf(nu[r * 8 + 3], (C0).w, d);                            \
            d = fmaf(nu[r * 8 + 4], (C1).x, d);                            \
            d = fmaf(nu[r * 8 + 5], (C1).y, d);                            \
            d = fmaf(nu[r * 8 + 6], (C1).z, d);                            \
            d = fmaf(nu[r * 8 + 7], (C1).w, d);                            \
            if (d < best[r]) { best[r] = d; bidx[r] = (NIDX); }            \
        }                                                                  \
    }

// ---------------- prep: per-row scale + nu = -2*(x/scale) ----------------
// Reduction order is VERBATIM the passing kernel's -> bit-identical scale.
__global__ __launch_bounds__(256) void prep_kernel(const float* __restrict__ x,
                                                   float* __restrict__ scale_out,
                                                   float* __restrict__ nuout) {
    int tid = threadIdx.x;
    int xr = blockIdx.x;                               // 0..15
    const float4* xv = (const float4*)(x + xr * X_COLS);
    float4 q0 = xv[tid];
    float4 q1 = xv[tid + 256];
    float s = fabsf(q0.x) + fabsf(q0.y) + fabsf(q0.z) + fabsf(q0.w)
            + fabsf(q1.x) + fabsf(q1.y) + fabsf(q1.z) + fabsf(q1.w);
    #pragma unroll
    for (int off = 32; off > 0; off >>= 1) s += __shfl_down(s, off, 64);
    __shared__ float ls[4];
    __shared__ float scale_sh;
    int wave = tid >> 6, lane = tid & 63;
    if (lane == 0) ls[wave] = s;
    __syncthreads();
    if (tid == 0) {
        float t = (ls[0] + ls[1] + ls[2] + ls[3]) * (1.0f / (float)X_COLS);
        scale_sh = t;
        scale_out[xr] = t;
    }
    __syncthreads();
    float scale = scale_sh;

    // nu = -2*(x/scale): same op composition as the passing kernels.
    float4 n0, n1;
    n0.x = -2.0f * (q0.x / scale);  n0.y = -2.0f * (q0.y / scale);
    n0.z = -2.0f * (q0.z / scale);  n0.w = -2.0f * (q0.w / scale);
    n1.x = -2.0f * (q1.x / scale);  n1.y = -2.0f * (q1.y / scale);
    n1.z = -2.0f * (q1.z / scale);  n1.w = -2.0f * (q1.w / scale);
    float4* np = (float4*)(nuout + xr * X_COLS);
    np[tid]       = n0;
    np[tid + 256] = n1;
}

// ---------------- argmin over the full codebook ----------------
// ROUND-6 CHANGE (the only one): 512 threads/block instead of 256.
// Round-5 diagnosis: grid-limited occupancy (2 waves/SIMD) left compiler-sunk
// L2 loads exposed (VALUBusy 74% -> 26% stall). 8 waves/block, 2 blocks/CU
// (LDS 2x32KB, SGPR ~112x4/SIMD <= 800) -> 4 waves/SIMD. Total VALU work,
// codebook traffic (512 x 2MB = 1GB L2), and numerics unchanged.
__global__ __launch_bounds__(AT, 4) void argmin_kernel(const float* __restrict__ cb,
                                                       const float* __restrict__ nuarr,
                                                       int* __restrict__ indices,
                                                       float* __restrict__ sums,
                                                       float* __restrict__ counts) {
    int tid = threadIdx.x;
    int m0 = blockIdx.x * RPB;

    // 64 wave-uniform nu via uniform-address loads -> s_load -> SGPRs.
    const float* __restrict__ up = nuarr + (size_t)m0 * CB_DIM;
    float nu[RPB * CB_DIM];
    #pragma unroll
    for (int i = 0; i < RPB * CB_DIM; i++) nu[i] = up[i];

    float best[RPB];
    int   bidx[RPB];
    #pragma unroll
    for (int r = 0; r < RPB; r++) { best[r] = 3.4e38f; bidx[r] = 0; }

    // ---- 4-wide ping-pong (round-5 structure, verified absmax 0.0).
    // Coverage: tid + AT*k, k=0..127. 32 groups of 4; loop 31 + peel.
    // Max prefetch: j=30 -> n+7*AT = tid+61440+3584 <= 65535.
    const float4* cp = (const float4*)cb;
    int n = tid;
    float4 a0 = cp[2 * n],            a1 = cp[2 * n + 1];
    float4 b0 = cp[2 * (n + AT)],     b1 = cp[2 * (n + AT) + 1];
    float4 c0 = cp[2 * (n + 2 * AT)], c1 = cp[2 * (n + 2 * AT) + 1];
    float4 d0 = cp[2 * (n + 3 * AT)], d1 = cp[2 * (n + 3 * AT) + 1];

    for (int j = 0; j < 31; j++) {
        CODE_BODY(a0, a1, n)
        CODE_BODY(b0, b1, n + AT)
        a0 = cp[2 * (n + 4 * AT)]; a1 = cp[2 * (n + 4 * AT) + 1];
        b0 = cp[2 * (n + 5 * AT)]; b1 = cp[2 * (n + 5 * AT) + 1];
        CODE_BODY(c0, c1, n + 2 * AT)
        CODE_BODY(d0, d1, n + 3 * AT)
        c0 = cp[2 * (n + 6 * AT)]; c1 = cp[2 * (n + 6 * AT) + 1];
        d0 = cp[2 * (n + 7 * AT)]; d1 = cp[2 * (n + 7 * AT) + 1];
        n += 4 * AT;
    }
    CODE_BODY(a0, a1, n)
    CODE_BODY(b0, b1, n + AT)
    CODE_BODY(c0, c1, n + 2 * AT)
    CODE_BODY(d0, d1, n + 3 * AT)

    // ---- cross-thread reduce: (sortable(dist)<<32)|idx, u64-min ----
    __shared__ unsigned long long red[RPB][AT];        // 32 KB
    #pragma unroll
    for (int r = 0; r < RPB; r++) {
        unsigned int b = __float_as_uint(best[r]);
        unsigned int k = b ^ ((unsigned int)((int)b >> 31) | 0x80000000u);
        red[r][tid] = ((unsigned long long)k << 32) | (unsigned int)bidx[r];
    }
    for (int t = AT / 2; t > 0; t >>= 1) {
        __syncthreads();
        if (tid < t) {
            #pragma unroll
            for (int r = 0; r < RPB; r++) {
                unsigned long long a = red[r][tid], c = red[r][tid + t];
                if (c < a) red[r][tid] = c;
            }
        }
    }
    __syncthreads();

    // indices + zero sums/counts at selected codes (kernel boundary orders
    // the zeros before accum; duplicate zero-writes are benign)
    if (tid < RPB) {
        int idx = (int)(red[tid][0] & 0xFFFFFFFFull);
        indices[m0 + tid] = idx;
        counts[idx] = 0.f;
        float4 z = make_float4(0.f, 0.f, 0.f, 0.f);
        float4* sp = (float4*)(sums + (size_t)idx * CB_DIM);
        sp[0] = z;
        sp[1] = z;
    }
}

// ---------------- segment-sum via atomics (128 blocks, 1 thr/(m,k)) ----------------
// nuarr holds -2u; sums accumulate -2*sum(u) EXACTLY (power-of-two scaling
// commutes with fp rounding, any atomic order). gather compensates.
__global__ __launch_bounds__(256) void accum_kernel(const int* __restrict__ indices,
                                                    const float* __restrict__ nuarr,
                                                    float* __restrict__ sums,
                                                    float* __restrict__ counts) {
    int e = blockIdx.x * blockDim.x + threadIdx.x;     // 0..32767, one per (m,k)
    int m = e >> 3, k = e & 7;
    int idx = indices[m];
    if (k == 0) atomicAdd(&counts[idx], 1.0f);
    atomicAdd(&sums[(size_t)idx * CB_DIM + k], nuarr[e]);
}

// ---------------- gather + rescale ----------------
__global__ __launch_bounds__(256) void gather_kernel(const int* __restrict__ indices,
                                                     const float* __restrict__ sums,
                                                     const float* __restrict__ counts,
                                                     const float* __restrict__ scale,
                                                     float* __restrict__ out) {
    int e = blockIdx.x * blockDim.x + threadIdx.x;     // 0..32767
    if (e < B_ROWS * X_COLS) {
        int m = e >> 3, k = e & 7;
        int idx = indices[m];
        float c = counts[idx];
        c = c < 1.f ? 1.f : c;
        // sums = -2*S exactly; (-0.5f)*(sums/c) == S/c bit-exactly.
        out[e] = scale[e >> 11] * (-0.5f * (sums[(size_t)idx * CB_DIM + k] / c));
    }
}

extern "C" void kernel_launch(void* const* d_in, const int* in_sizes, int n_in,
                              void* d_out, int out_size, void* d_ws, size_t ws_size,
                              hipStream_t stream) {
    const float* x  = (const float*)d_in[0];           // [16,2048]
    const float* cb = (const float*)d_in[1];           // [65536,8]
    char* ws = (char*)d_ws;
    float* scale   = (float*)(ws + WS_SCALE);
    int*   indices = (int*)(ws + WS_IDX);
    float* nuarr   = (float*)(ws + WS_U);
    float* sums    = (float*)(ws + WS_SUMS);
    float* counts  = (float*)(ws + WS_CNT);
    float* out     = (float*)d_out;

    prep_kernel  <<<B_ROWS, 256, 0, stream>>>(x, scale, nuarr);
    argmin_kernel<<<M_ROWS / RPB, AT, 0, stream>>>(cb, nuarr, indices, sums, counts);
    accum_kernel <<<(M_ROWS * CB_DIM) / 256, 256, 0, stream>>>(indices, nuarr, sums, counts);
    gather_kernel<<<(B_ROWS * X_COLS) / 256, 256, 0, stream>>>(indices, sums, counts, scale, out);
}